// Round 6
// baseline (294.707 us; speedup 1.0000x reference)
//
#include <hip/hip_runtime.h>
#include <hip/hip_bf16.h>
#include <stdint.h>

// Problem constants
#define B_  4
#define S_  2048
#define DM  512
#define H_  8
#define DK  64

typedef float        f32x4 __attribute__((ext_vector_type(4)));
typedef short        s16x8 __attribute__((ext_vector_type(8)));
typedef short        s16x4 __attribute__((ext_vector_type(4)));
typedef unsigned int u32x4 __attribute__((ext_vector_type(4)));
typedef unsigned long long u64x4 __attribute__((ext_vector_type(4)));

#define MFMA_B16(a,b,c) __builtin_amdgcn_mfma_f32_16x16x32_bf16(a,b,c,0,0,0)

__device__ __forceinline__ uint32_t bfr(float x) {           // fp32 -> bf16 bits, RNE
  uint32_t u = __float_as_uint(x);
  return (u + 0x7fffu + ((u >> 16) & 1u)) >> 16;
}
__device__ __forceinline__ uint32_t pk2(float a, float b) {  // pack 2 bf16
  return ((bfr(b) & 0xffffu) << 16) | (bfr(a) & 0xffffu);
}
__device__ __forceinline__ float uf16(short s) {             // bf16 bits -> fp32
  return __uint_as_float(((uint32_t)(uint16_t)s) << 16);
}

// ---------------------------------------------------------------------------
// Weight transpose + convert via LDS tile: Wt[z][n][k] (bf16) = W_z[k][n]
// ---------------------------------------------------------------------------
__global__ __launch_bounds__(256) void wt_k(const float* __restrict__ w0,
                                            const float* __restrict__ w1,
                                            const float* __restrict__ w2,
                                            const float* __restrict__ w3,
                                            uint16_t* __restrict__ Wt) {
  __shared__ float Ls[64 * 65];
  const int tid = threadIdx.x;
  const int z = blockIdx.z;
  const float* W = (z == 0) ? w0 : (z == 1) ? w1 : (z == 2) ? w2 : w3;
  const int k0 = blockIdx.x * 64, n0 = blockIdx.y * 64;
  {
    const int r = tid >> 2, c = (tid & 3) * 16;
    const float4* src = (const float4*)(W + (size_t)(k0 + r) * 512 + n0 + c);
    float4 v0 = src[0], v1 = src[1], v2 = src[2], v3 = src[3];
    float* d = Ls + r * 65 + c;
    d[0]=v0.x; d[1]=v0.y; d[2]=v0.z;  d[3]=v0.w;
    d[4]=v1.x; d[5]=v1.y; d[6]=v1.z;  d[7]=v1.w;
    d[8]=v2.x; d[9]=v2.y; d[10]=v2.z; d[11]=v2.w;
    d[12]=v3.x;d[13]=v3.y;d[14]=v3.z; d[15]=v3.w;
  }
  __syncthreads();
  uint16_t* dstbase = Wt + (size_t)z * 262144;
#pragma unroll
  for (int i = 0; i < 2; ++i) {
    int nl = i * 32 + (tid >> 3);
    int kc = (tid & 7) * 8;
    s16x8 v;
#pragma unroll
    for (int jj = 0; jj < 8; ++jj) v[jj] = (short)bfr(Ls[(kc + jj) * 65 + nl]);
    *(s16x8*)(dstbase + (size_t)(n0 + nl) * 512 + k0 + kc) = v;
  }
}

// ---------------------------------------------------------------------------
// Mask pack: int32 [4,2048,2048] -> 64-bit words [4,2048,32] (bit k = masked)
// ---------------------------------------------------------------------------
__global__ __launch_bounds__(256) void maskpack_k(const int* __restrict__ mask,
                                                  unsigned long long* __restrict__ mbits) {
  const int lane = threadIdx.x & 63;
  const int wid = (blockIdx.x * 256 + threadIdx.x) >> 6;   // 0..8191
  for (int w0 = wid * 4; w0 < B_ * S_ * 32; w0 += 8192 * 4) {
    int v0 = __builtin_nontemporal_load(mask + (size_t)(w0 + 0) * 64 + lane);
    int v1 = __builtin_nontemporal_load(mask + (size_t)(w0 + 1) * 64 + lane);
    int v2 = __builtin_nontemporal_load(mask + (size_t)(w0 + 2) * 64 + lane);
    int v3 = __builtin_nontemporal_load(mask + (size_t)(w0 + 3) * 64 + lane);
    unsigned long long b0 = __ballot(v0 != 0), b1 = __ballot(v1 != 0);
    unsigned long long b2 = __ballot(v2 != 0), b3 = __ballot(v3 != 0);
    if (lane == 0) { u64x4 t = {b0, b1, b2, b3}; *(u64x4*)(mbits + w0) = t; }
  }
}

// ---------------------------------------------------------------------------
// GEMM: C[M,N] = A[M,K=512] @ Bt[N,K]^T, BM=BN=64, BK=64, 4 waves (2x2).
// ---------------------------------------------------------------------------
template <bool PROJ>
__global__ __launch_bounds__(256) void gemm2_k(const float* __restrict__ Xq,
                                               const float* __restrict__ Xk,
                                               const float* __restrict__ Xv,
                                               const uint16_t* __restrict__ Wt,
                                               const uint16_t* __restrict__ Actx,
                                               uint16_t* __restrict__ Qkv,
                                               float* __restrict__ Y) {
  __shared__ __hip_bfloat16 As[64 * 64];
  __shared__ __hip_bfloat16 Bs[64 * 64];
  const int tid = threadIdx.x, lane = tid & 63, w = tid >> 6;
  const int l4 = lane >> 4, lc = lane & 15;
  const int p = blockIdx.x;
  const int L = PROJ ? ((p & 7) * 384 + (p >> 3)) : ((p & 7) * 128 + (p >> 3));
  const int yn = L & 7;
  const int xm = PROJ ? ((L >> 3) & 127) : (L >> 3);
  const int z  = PROJ ? (L >> 10) : 3;
  const int m0 = xm * 64, n0 = yn * 64;
  const float* Af = PROJ ? ((z == 0) ? Xq : (z == 1) ? Xk : Xv) : nullptr;
  const uint16_t* Bt = Wt + (size_t)z * 262144;
  const int wm = (w >> 1) * 32, wn = (w & 1) * 32;
  const int ar = tid >> 2, ac = (tid & 3) * 16;
  f32x4 acc[2][2] = {};

  float4 ra[4]; s16x8 rab[2]; s16x8 rb[2];
  auto loadA = [&](int kk) {
    if constexpr (PROJ) {
      const float4* s = (const float4*)(Af + (size_t)(m0 + ar) * 512 + kk + ac);
      ra[0] = s[0]; ra[1] = s[1]; ra[2] = s[2]; ra[3] = s[3];
    } else {
      const uint16_t* s = Actx + (size_t)(m0 + ar) * 512 + kk + ac;
      rab[0] = *(const s16x8*)s; rab[1] = *(const s16x8*)(s + 8);
    }
  };
  auto loadB = [&](int kk) {
    const uint16_t* s = Bt + (size_t)(n0 + ar) * 512 + kk + ac;
    rb[0] = *(const s16x8*)s; rb[1] = *(const s16x8*)(s + 8);
  };
  auto writeAB = [&]() {
    char* da = (char*)As + ar * 128;
    char* db = (char*)Bs + ar * 128;
    const int c0 = (ac * 2) ^ ((ar & 7) << 4);
    const int c1 = (ac * 2 + 16) ^ ((ar & 7) << 4);
    if constexpr (PROJ) {
      u32x4 p0, p1;
      p0.x = pk2(ra[0].x, ra[0].y); p0.y = pk2(ra[0].z, ra[0].w);
      p0.z = pk2(ra[1].x, ra[1].y); p0.w = pk2(ra[1].z, ra[1].w);
      p1.x = pk2(ra[2].x, ra[2].y); p1.y = pk2(ra[2].z, ra[2].w);
      p1.z = pk2(ra[3].x, ra[3].y); p1.w = pk2(ra[3].z, ra[3].w);
      *(u32x4*)(da + c0) = p0; *(u32x4*)(da + c1) = p1;
    } else {
      *(s16x8*)(da + c0) = rab[0]; *(s16x8*)(da + c1) = rab[1];
    }
    *(s16x8*)(db + c0) = rb[0]; *(s16x8*)(db + c1) = rb[1];
  };

  loadA(0); loadB(0); writeAB();
  __syncthreads();
  for (int t = 0; t < 8; ++t) {
    if (t < 7) { loadA((t + 1) * 64); loadB((t + 1) * 64); }
    s16x8 af[2], bg[2];
    __builtin_amdgcn_s_setprio(1);
#pragma unroll
    for (int kf = 0; kf < 2; ++kf) {
#pragma unroll
      for (int mf = 0; mf < 2; ++mf) {
        int row = wm + mf * 16 + lc;
        af[mf] = *(const s16x8*)((char*)As + row * 128 +
                                 ((kf * 64 + l4 * 16) ^ ((row & 7) << 4)));
      }
#pragma unroll
      for (int nf = 0; nf < 2; ++nf) {
        int row = wn + nf * 16 + lc;
        bg[nf] = *(const s16x8*)((char*)Bs + row * 128 +
                                 ((kf * 64 + l4 * 16) ^ ((row & 7) << 4)));
      }
#pragma unroll
      for (int mf = 0; mf < 2; ++mf)
#pragma unroll
        for (int nf = 0; nf < 2; ++nf)
          acc[mf][nf] = MFMA_B16(af[mf], bg[nf], acc[mf][nf]);
    }
    __builtin_amdgcn_s_setprio(0);
    if (t < 7) {
      __syncthreads();
      writeAB();
      __syncthreads();
    }
  }
#pragma unroll
  for (int mf = 0; mf < 2; ++mf)
#pragma unroll
    for (int nf = 0; nf < 2; ++nf) {
      int row = m0 + wm + mf * 16 + l4 * 4;
      int col = n0 + wn + nf * 16 + lc;
#pragma unroll
      for (int j = 0; j < 4; ++j) {
        if constexpr (PROJ)
          (Qkv + (size_t)z * 4194304)[(size_t)(row + j) * 512 + col] =
              (uint16_t)bfr(acc[mf][nf][j]);
        else
          Y[(size_t)(row + j) * 512 + col] = acc[mf][nf][j];
      }
    }
}

// ---------------------------------------------------------------------------
// Fused 2-pass attention (m==0 softmax). Round-6 change (ONE variable):
// pass-2 attn stores are PLAIN (write-back via L2) instead of nontemporal.
// ---------------------------------------------------------------------------
__global__ __launch_bounds__(256) void attn_k(const uint16_t* __restrict__ Qb,
                                              const uint16_t* __restrict__ Kb,
                                              const uint16_t* __restrict__ Vb,
                                              const unsigned long long* __restrict__ mbits,
                                              float* __restrict__ attn_out,
                                              uint16_t* __restrict__ ctx) {
  __shared__ __hip_bfloat16 Ks[2][64 * 64];     // [buf][k][d], XOR (row&7)<<4
  __shared__ __hip_bfloat16 Vt[64 * 64];        // [d][k],  XOR ((d>>3)&7)<<4
  __shared__ __hip_bfloat16 Ps[4][16 * 72];     // per-wave P, rows 144B
  const int tid = threadIdx.x, lane = tid & 63, w = tid >> 6;
  const int l4 = lane >> 4, lc = lane & 15;
  const int p = blockIdx.x;
  const int L = (p & 7) * 128 + (p >> 3);
  const int qt = L & 31, h = (L >> 5) & 7, b = L >> 8;
  const int qbase = qt * 64;
  const int srow = tid >> 3, scol = tid & 7;

  s16x8 aq0, aq1;
  {
    const uint16_t* qp = Qb + ((size_t)(b * S_ + qbase + w * 16 + lc)) * DM + h * DK + l4 * 8;
    aq0 = *(const s16x8*)qp;
    aq1 = *(const s16x8*)(qp + 32);
  }
  const uint16_t* Kbase = Kb + (size_t)(b * S_) * DM + h * DK;
  const uint16_t* Vbase = Vb + (size_t)(b * S_) * DM + h * DK;
  const unsigned long long* mrow = mbits + ((size_t)(b * S_) + qbase + w * 16 + l4 * 4) * 32;

  // ======================= pass 1: l only (m == 0) =======================
  float lrun[4] = {0.f, 0.f, 0.f, 0.f};
#pragma unroll
  for (int i = 0; i < 2; ++i) {
    int row = i * 32 + srow;
    s16x8 v = *(const s16x8*)(Kbase + (size_t)row * DM + scol * 8);
    *(s16x8*)((char*)Ks[0] + row * 128 + ((scol * 16) ^ ((row & 7) << 4))) = v;
  }
  __syncthreads();
  for (int kt = 0; kt < 32; ++kt) {
    const int cur = kt & 1;
    const int nxt = (kt < 31) ? kt + 1 : kt;
    s16x8 rk0 = *(const s16x8*)(Kbase + (size_t)(nxt * 64 + srow) * DM + scol * 8);
    s16x8 rk1 = *(const s16x8*)(Kbase + (size_t)(nxt * 64 + 32 + srow) * DM + scol * 8);
    unsigned long long mws[4];
#pragma unroll
    for (int j = 0; j < 4; ++j) mws[j] = mrow[j * 32 + kt];
    f32x4 sacc[4] = {};
    __builtin_amdgcn_s_setprio(1);
#pragma unroll
    for (int nf = 0; nf < 4; ++nf) {
      int row = nf * 16 + lc;
#pragma unroll
      for (int kf = 0; kf < 2; ++kf) {
        s16x8 bk = *(const s16x8*)((char*)Ks[cur] + row * 128 +
                                   ((kf * 64 + l4 * 16) ^ ((row & 7) << 4)));
        sacc[nf] = MFMA_B16(kf ? aq1 : aq0, bk, sacc[nf]);
      }
    }
    __builtin_amdgcn_s_setprio(0);
#pragma unroll
    for (int j = 0; j < 4; ++j)
#pragma unroll
      for (int nf = 0; nf < 4; ++nf) {
        float e = __expf(sacc[nf][j] * 0.125f);
        lrun[j] += ((mws[j] >> (nf * 16 + lc)) & 1ull) ? 0.f : e;
      }
    *(s16x8*)((char*)Ks[cur ^ 1] + srow * 128 + ((scol * 16) ^ ((srow & 7) << 4))) = rk0;
    {
      int row = 32 + srow;
      *(s16x8*)((char*)Ks[cur ^ 1] + row * 128 + ((scol * 16) ^ ((row & 7) << 4))) = rk1;
    }
    __syncthreads();
  }
#pragma unroll
  for (int off = 1; off < 16; off <<= 1)
#pragma unroll
    for (int j = 0; j < 4; ++j) lrun[j] += __shfl_xor(lrun[j], off);
  float Li[4];
#pragma unroll
  for (int j = 0; j < 4; ++j) Li[j] = 1.f / lrun[j];

  // ======================= pass 2: write attn + PV =======================
#pragma unroll
  for (int i = 0; i < 2; ++i) {
    int row = i * 32 + srow;
    s16x8 v = *(const s16x8*)(Kbase + (size_t)row * DM + scol * 8);
    *(s16x8*)((char*)Ks[0] + row * 128 + ((scol * 16) ^ ((row & 7) << 4))) = v;
    s16x8 vv = *(const s16x8*)(Vbase + (size_t)row * DM + scol * 8);
#pragma unroll
    for (int jj = 0; jj < 8; ++jj) {
      int d = scol * 8 + jj;
      *(int16_t*)((char*)Vt + ((d * 128 + row * 2) ^ (scol << 4))) = vv[jj];
    }
  }
  __syncthreads();
  f32x4 cacc[4] = {};
  // row-contiguous store base: wave covers q rows [qbase+w*16, +16)
  float* arow = attn_out + (((size_t)(b * H_ + h)) * S_ + qbase + w * 16) * S_;
  for (int kt = 0; kt < 32; ++kt) {
    const int cur = kt & 1;
    const int nxt = (kt < 31) ? kt + 1 : kt;
    s16x8 rk0 = *(const s16x8*)(Kbase + (size_t)(nxt * 64 + srow) * DM + scol * 8);
    s16x8 rk1 = *(const s16x8*)(Kbase + (size_t)(nxt * 64 + 32 + srow) * DM + scol * 8);
    s16x8 rv0 = *(const s16x8*)(Vbase + (size_t)(nxt * 64 + srow) * DM + scol * 8);
    s16x8 rv1 = *(const s16x8*)(Vbase + (size_t)(nxt * 64 + 32 + srow) * DM + scol * 8);
    unsigned long long mws[4];
#pragma unroll
    for (int j = 0; j < 4; ++j) mws[j] = mrow[j * 32 + kt];
    f32x4 sacc[4] = {};
    __builtin_amdgcn_s_setprio(1);
#pragma unroll
    for (int nf = 0; nf < 4; ++nf) {
      int row = nf * 16 + lc;
#pragma unroll
      for (int kf = 0; kf < 2; ++kf) {
        s16x8 bk = *(const s16x8*)((char*)Ks[cur] + row * 128 +
                                   ((kf * 64 + l4 * 16) ^ ((row & 7) << 4)));
        sacc[nf] = MFMA_B16(kf ? aq1 : aq0, bk, sacc[nf]);
      }
    }
    __builtin_amdgcn_s_setprio(0);
#pragma unroll
    for (int j = 0; j < 4; ++j)
#pragma unroll
      for (int nf = 0; nf < 4; ++nf) {
        float e = __expf(sacc[nf][j] * 0.125f);
        float p2 = ((mws[j] >> (nf * 16 + lc)) & 1ull) ? 0.f : e * Li[j];
        *(uint16_t*)((char*)Ps[w] + (l4 * 4 + j) * 144 + (nf * 16 + lc) * 2) = (uint16_t)bfr(p2);
      }
    // PV fragments (row = lc, k contiguous)
    s16x8 ap0 = *(const s16x8*)((char*)Ps[w] + lc * 144 + l4 * 16);
    s16x8 ap1 = *(const s16x8*)((char*)Ps[w] + lc * 144 + 64 + l4 * 16);
    // attn store: row-contiguous readback; per instruction 4 rows x 256B packed
#pragma unroll
    for (int j = 0; j < 4; ++j) {
      const int r = j * 4 + (lane >> 4);
      s16x4 pv = *(const s16x4*)((char*)Ps[w] + r * 144 + (lane & 15) * 8);
      f32x4 o;
      o[0] = uf16(pv[0]); o[1] = uf16(pv[1]); o[2] = uf16(pv[2]); o[3] = uf16(pv[3]);
      *(f32x4*)(arow + (size_t)r * S_ + kt * 64 + (lane & 15) * 4) = o;   // PLAIN store
    }
    __builtin_amdgcn_s_setprio(1);
#pragma unroll
    for (int nf = 0; nf < 4; ++nf) {
      int d = nf * 16 + lc;
#pragma unroll
      for (int kf = 0; kf < 2; ++kf) {
        s16x8 bv = *(const s16x8*)((char*)Vt +
                     ((d * 128 + kf * 64 + l4 * 16) ^ ((((d >> 3)) & 7) << 4)));
        cacc[nf] = MFMA_B16(kf ? ap1 : ap0, bv, cacc[nf]);
      }
    }
    __builtin_amdgcn_s_setprio(0);
    __syncthreads();
    *(s16x8*)((char*)Ks[cur ^ 1] + srow * 128 + ((scol * 16) ^ ((srow & 7) << 4))) = rk0;
    {
      int row = 32 + srow;
      *(s16x8*)((char*)Ks[cur ^ 1] + row * 128 + ((scol * 16) ^ ((row & 7) << 4))) = rk1;
    }
#pragma unroll
    for (int jj = 0; jj < 8; ++jj) {
      int d = scol * 8 + jj;
      *(int16_t*)((char*)Vt + ((d * 128 + srow * 2) ^ (scol << 4))) = rv0[jj];
      *(int16_t*)((char*)Vt + ((d * 128 + (32 + srow) * 2) ^ (scol << 4))) = rv1[jj];
    }
    __syncthreads();
  }
#pragma unroll
  for (int nf = 0; nf < 4; ++nf) {
    int d = nf * 16 + lc;
#pragma unroll
    for (int j = 0; j < 4; ++j) {
      int q = qbase + w * 16 + l4 * 4 + j;
      ctx[((size_t)(b * S_ + q)) * DM + h * DK + d] = (uint16_t)bfr(cacc[nf][j]);
    }
  }
}

// ---------------------------------------------------------------------------
// Residual + LayerNorm: out = LN(Y + Xq), one wave per 512-wide row
// ---------------------------------------------------------------------------
__global__ __launch_bounds__(256) void ln_k(const float* __restrict__ Y,
                                            const float* __restrict__ X,
                                            float* __restrict__ out) {
  const int lane = threadIdx.x & 63, w = threadIdx.x >> 6;
  const size_t row = (size_t)blockIdx.x * 4 + w;
  const float4* y = (const float4*)(Y + row * 512);
  const float4* x = (const float4*)(X + row * 512);
  float4 a0 = y[lane * 2], a1 = y[lane * 2 + 1];
  float4 b0 = x[lane * 2], b1 = x[lane * 2 + 1];
  float v[8] = {a0.x + b0.x, a0.y + b0.y, a0.z + b0.z, a0.w + b0.w,
                a1.x + b1.x, a1.y + b1.y, a1.z + b1.z, a1.w + b1.w};
  float s = 0.f, ss = 0.f;
#pragma unroll
  for (int j = 0; j < 8; ++j) { s += v[j]; ss += v[j] * v[j]; }
#pragma unroll
  for (int off = 1; off < 64; off <<= 1) {
    s += __shfl_xor(s, off);
    ss += __shfl_xor(ss, off);
  }
  float mean = s * (1.f / 512.f);
  float var = ss * (1.f / 512.f) - mean * mean;
  float rstd = rsqrtf(var + 1e-5f);
  float4 o0 = make_float4((v[0] - mean) * rstd, (v[1] - mean) * rstd,
                          (v[2] - mean) * rstd, (v[3] - mean) * rstd);
  float4 o1 = make_float4((v[4] - mean) * rstd, (v[5] - mean) * rstd,
                          (v[6] - mean) * rstd, (v[7] - mean) * rstd);
  float4* o = (float4*)(out + row * 512);
  o[lane * 2] = o0;
  o[lane * 2 + 1] = o1;
}

// ---------------------------------------------------------------------------
extern "C" void kernel_launch(void* const* d_in, const int* in_sizes, int n_in,
                              void* d_out, int out_size, void* d_ws, size_t ws_size,
                              hipStream_t stream) {
  const float* Xq = (const float*)d_in[0];
  const float* Xk = (const float*)d_in[1];
  const float* Xv = (const float*)d_in[2];
  const int*   mask = (const int*)d_in[3];
  const float* Wq = (const float*)d_in[4];
  const float* Wk = (const float*)d_in[5];
  const float* Wv = (const float*)d_in[6];
  const float* Wo = (const float*)d_in[7];

  float* out  = (float*)d_out;
  float* attn = out + (size_t)B_ * S_ * DM;

  char* ws = (char*)d_ws;
  uint16_t* Qb = (uint16_t*)(ws);                        //  0 .. 8M   bf16 [8192][512]
  uint16_t* Kb = (uint16_t*)(ws + (8u  << 20));          //  8 .. 16M
  uint16_t* Vb = (uint16_t*)(ws + (16u << 20));          // 16 .. 24M
  uint16_t* Cx = (uint16_t*)(ws + (24u << 20));          // 24 .. 32M  context bf16
  float*    Y  = (float*)   (ws + (32u << 20));          // 32 .. 48M  fp32 [8192][512]
  uint16_t* Wt = (uint16_t*)(ws + (48u << 20));          // 48 .. 50M  4x[512][512] bf16
  unsigned long long* mb = (unsigned long long*)(ws + (50u << 20));  // 50 .. 52M

  wt_k<<<dim3(8, 8, 4), 256, 0, stream>>>(Wq, Wk, Wv, Wo, Wt);
  maskpack_k<<<2048, 256, 0, stream>>>(mask, mb);

  gemm2_k<true><<<3072, 256, 0, stream>>>(Xq, Xk, Xv, Wt, nullptr, Qb, nullptr);

  attn_k<<<1024, 256, 0, stream>>>(Qb, Kb, Vb, mb, attn, Cx);

  gemm2_k<false><<<1024, 256, 0, stream>>>(nullptr, nullptr, nullptr, Wt, Cx, nullptr, Y);
  ln_k<<<2048, 256, 0, stream>>>(Y, Xq, out);
}

// Round 7
// 226.646 us; speedup vs baseline: 1.3003x; 1.3003x over previous
//
#include <hip/hip_runtime.h>
#include <hip/hip_bf16.h>
#include <stdint.h>

// Problem constants
#define B_  4
#define S_  2048
#define DM  512
#define H_  8
#define DK  64

typedef float        f32x4 __attribute__((ext_vector_type(4)));
typedef short        s16x8 __attribute__((ext_vector_type(8)));
typedef short        s16x4 __attribute__((ext_vector_type(4)));
typedef unsigned int u32x4 __attribute__((ext_vector_type(4)));
typedef unsigned long long u64x4 __attribute__((ext_vector_type(4)));

#define MFMA_B16(a,b,c) __builtin_amdgcn_mfma_f32_16x16x32_bf16(a,b,c,0,0,0)

__device__ __forceinline__ uint32_t bfr(float x) {           // fp32 -> bf16 bits, RNE
  uint32_t u = __float_as_uint(x);
  return (u + 0x7fffu + ((u >> 16) & 1u)) >> 16;
}
__device__ __forceinline__ uint32_t pk2(float a, float b) {  // pack 2 bf16
  return ((bfr(b) & 0xffffu) << 16) | (bfr(a) & 0xffffu);
}
__device__ __forceinline__ float uf16(short s) {             // bf16 bits -> fp32
  return __uint_as_float(((uint32_t)(uint16_t)s) << 16);
}

// ---------------------------------------------------------------------------
// prep_k: fused weight-transpose (blocks 0..255) + mask pack (blocks 256..2303)
// ---------------------------------------------------------------------------
__global__ __launch_bounds__(256) void prep_k(const float* __restrict__ w0,
                                              const float* __restrict__ w1,
                                              const float* __restrict__ w2,
                                              const float* __restrict__ w3,
                                              uint16_t* __restrict__ Wt,
                                              const int* __restrict__ mask,
                                              unsigned long long* __restrict__ mbits) {
  __shared__ float Ls[64 * 65];
  const int tid = threadIdx.x;
  if (blockIdx.x < 256) {
    const int bx = blockIdx.x;
    const int z = bx >> 6;
    const int k0 = ((bx >> 3) & 7) * 64, n0 = (bx & 7) * 64;
    const float* W = (z == 0) ? w0 : (z == 1) ? w1 : (z == 2) ? w2 : w3;
    {
      const int r = tid >> 2, c = (tid & 3) * 16;
      const float4* src = (const float4*)(W + (size_t)(k0 + r) * 512 + n0 + c);
      float4 v0 = src[0], v1 = src[1], v2 = src[2], v3 = src[3];
      float* d = Ls + r * 65 + c;
      d[0]=v0.x; d[1]=v0.y; d[2]=v0.z;  d[3]=v0.w;
      d[4]=v1.x; d[5]=v1.y; d[6]=v1.z;  d[7]=v1.w;
      d[8]=v2.x; d[9]=v2.y; d[10]=v2.z; d[11]=v2.w;
      d[12]=v3.x;d[13]=v3.y;d[14]=v3.z; d[15]=v3.w;
    }
    __syncthreads();
    uint16_t* dstbase = Wt + (size_t)z * 262144;
#pragma unroll
    for (int i = 0; i < 2; ++i) {
      int nl = i * 32 + (tid >> 3);
      int kc = (tid & 7) * 8;
      s16x8 v;
#pragma unroll
      for (int jj = 0; jj < 8; ++jj) v[jj] = (short)bfr(Ls[(kc + jj) * 65 + nl]);
      *(s16x8*)(dstbase + (size_t)(n0 + nl) * 512 + k0 + kc) = v;
    }
  } else {
    const int lane = tid & 63;
    const int wid = ((blockIdx.x - 256) * 256 + tid) >> 6;   // 0..8191
    for (int w0i = wid * 4; w0i < B_ * S_ * 32; w0i += 8192 * 4) {
      int v0 = __builtin_nontemporal_load(mask + (size_t)(w0i + 0) * 64 + lane);
      int v1 = __builtin_nontemporal_load(mask + (size_t)(w0i + 1) * 64 + lane);
      int v2 = __builtin_nontemporal_load(mask + (size_t)(w0i + 2) * 64 + lane);
      int v3 = __builtin_nontemporal_load(mask + (size_t)(w0i + 3) * 64 + lane);
      unsigned long long b0 = __ballot(v0 != 0), b1 = __ballot(v1 != 0);
      unsigned long long b2 = __ballot(v2 != 0), b3 = __ballot(v3 != 0);
      if (lane == 0) { u64x4 t = {b0, b1, b2, b3}; *(u64x4*)(mbits + w0i) = t; }
    }
  }
}

// ---------------------------------------------------------------------------
// GEMM 128x128 tile: C[M,N] = A[M,K=512] @ Bt[N,K]^T. BK=64, 4 waves (2x2),
// each wave 64x64 out (4x4 frags of 16x16x32). Reg-prefetch next K-tile.
// PROJ: A fp32 (Xq/Xk/Xv by z), C bf16 Qkv.  !PROJ: A bf16 ctx, C fp32 Y.
// ---------------------------------------------------------------------------
template <bool PROJ>
__global__ __launch_bounds__(256) void gemm3_k(const float* __restrict__ Xq,
                                               const float* __restrict__ Xk,
                                               const float* __restrict__ Xv,
                                               const uint16_t* __restrict__ Wt,
                                               const uint16_t* __restrict__ Actx,
                                               uint16_t* __restrict__ Qkv,
                                               float* __restrict__ Y) {
  __shared__ __hip_bfloat16 As[128 * 64];
  __shared__ __hip_bfloat16 Bs[128 * 64];
  const int tid = threadIdx.x, lane = tid & 63, w = tid >> 6;
  const int l4 = lane >> 4, lc = lane & 15;
  // --- XCD chunked swizzle; proj: 768 blocks (96/XCD), O: 256 (32/XCD).
  const int p = blockIdx.x;
  int xm, yn, z;
  if constexpr (PROJ) {
    const int L = (p & 7) * 96 + (p >> 3);
    z = L >> 8; const int r = L & 255; xm = r >> 2; yn = r & 3;
  } else {
    const int L = (p & 7) * 32 + (p >> 3);
    z = 3; xm = L >> 2; yn = L & 3;
  }
  const int m0 = xm * 128, n0 = yn * 128;
  const float* Af = PROJ ? ((z == 0) ? Xq : (z == 1) ? Xk : Xv) : nullptr;
  const uint16_t* Bt = Wt + (size_t)z * 262144;
  const int wm = (w >> 1) * 64, wn = (w & 1) * 64;
  const int srow = tid >> 3;                    // 0..31
  const int scol = tid & 7;                     // 0..7
  f32x4 acc[4][4] = {};

  float4 raA[4], raB[4]; s16x8 rab[4]; s16x8 rb[4];
  auto loadA = [&](int kk) {
#pragma unroll
    for (int i = 0; i < 4; ++i) {
      int row = i * 32 + srow;
      if constexpr (PROJ) {
        const float4* s = (const float4*)(Af + (size_t)(m0 + row) * 512 + kk + scol * 8);
        raA[i] = s[0]; raB[i] = s[1];
      } else {
        rab[i] = *(const s16x8*)(Actx + (size_t)(m0 + row) * 512 + kk + scol * 8);
      }
    }
  };
  auto loadB = [&](int kk) {
#pragma unroll
    for (int i = 0; i < 4; ++i) {
      int row = i * 32 + srow;
      rb[i] = *(const s16x8*)(Bt + (size_t)(n0 + row) * 512 + kk + scol * 8);
    }
  };
  auto writeAB = [&]() {
#pragma unroll
    for (int i = 0; i < 4; ++i) {
      int row = i * 32 + srow;
      const int c = (scol * 16) ^ ((row & 7) << 4);
      if constexpr (PROJ) {
        u32x4 v;
        v.x = pk2(raA[i].x, raA[i].y); v.y = pk2(raA[i].z, raA[i].w);
        v.z = pk2(raB[i].x, raB[i].y); v.w = pk2(raB[i].z, raB[i].w);
        *(u32x4*)((char*)As + row * 128 + c) = v;
      } else {
        *(s16x8*)((char*)As + row * 128 + c) = rab[i];
      }
      *(s16x8*)((char*)Bs + row * 128 + c) = rb[i];
    }
  };

  loadA(0); loadB(0); writeAB();
  __syncthreads();
  for (int t = 0; t < 8; ++t) {
    if (t < 7) { loadA((t + 1) * 64); loadB((t + 1) * 64); }
    __builtin_amdgcn_s_setprio(1);
#pragma unroll
    for (int kf = 0; kf < 2; ++kf) {
      s16x8 af[4], bg[4];
#pragma unroll
      for (int mf = 0; mf < 4; ++mf) {
        int row = wm + mf * 16 + lc;
        af[mf] = *(const s16x8*)((char*)As + row * 128 +
                                 ((kf * 64 + l4 * 16) ^ ((row & 7) << 4)));
      }
#pragma unroll
      for (int nf = 0; nf < 4; ++nf) {
        int row = wn + nf * 16 + lc;
        bg[nf] = *(const s16x8*)((char*)Bs + row * 128 +
                                 ((kf * 64 + l4 * 16) ^ ((row & 7) << 4)));
      }
#pragma unroll
      for (int mf = 0; mf < 4; ++mf)
#pragma unroll
        for (int nf = 0; nf < 4; ++nf)
          acc[mf][nf] = MFMA_B16(af[mf], bg[nf], acc[mf][nf]);
    }
    __builtin_amdgcn_s_setprio(0);
    if (t < 7) {
      __syncthreads();
      writeAB();
      __syncthreads();
    }
  }
#pragma unroll
  for (int mf = 0; mf < 4; ++mf)
#pragma unroll
    for (int nf = 0; nf < 4; ++nf) {
      int row = m0 + wm + mf * 16 + l4 * 4;
      int col = n0 + wn + nf * 16 + lc;
#pragma unroll
      for (int j = 0; j < 4; ++j) {
        if constexpr (PROJ)
          (Qkv + (size_t)z * 4194304)[(size_t)(row + j) * 512 + col] =
              (uint16_t)bfr(acc[mf][nf][j]);
        else
          Y[(size_t)(row + j) * 512 + col] = acc[mf][nf][j];
      }
    }
}

// ---------------------------------------------------------------------------
// Fused 2-pass attention (m==0 softmax). Round-5 config restored:
// nontemporal packed 256B-row stores (best measured).
// ---------------------------------------------------------------------------
__global__ __launch_bounds__(256) void attn_k(const uint16_t* __restrict__ Qb,
                                              const uint16_t* __restrict__ Kb,
                                              const uint16_t* __restrict__ Vb,
                                              const unsigned long long* __restrict__ mbits,
                                              float* __restrict__ attn_out,
                                              uint16_t* __restrict__ ctx) {
  __shared__ __hip_bfloat16 Ks[2][64 * 64];     // [buf][k][d], XOR (row&7)<<4
  __shared__ __hip_bfloat16 Vt[64 * 64];        // [d][k],  XOR ((d>>3)&7)<<4
  __shared__ __hip_bfloat16 Ps[4][16 * 72];     // per-wave P, rows 144B
  const int tid = threadIdx.x, lane = tid & 63, w = tid >> 6;
  const int l4 = lane >> 4, lc = lane & 15;
  const int p = blockIdx.x;
  const int L = (p & 7) * 128 + (p >> 3);
  const int qt = L & 31, h = (L >> 5) & 7, b = L >> 8;
  const int qbase = qt * 64;
  const int srow = tid >> 3, scol = tid & 7;

  s16x8 aq0, aq1;
  {
    const uint16_t* qp = Qb + ((size_t)(b * S_ + qbase + w * 16 + lc)) * DM + h * DK + l4 * 8;
    aq0 = *(const s16x8*)qp;
    aq1 = *(const s16x8*)(qp + 32);
  }
  const uint16_t* Kbase = Kb + (size_t)(b * S_) * DM + h * DK;
  const uint16_t* Vbase = Vb + (size_t)(b * S_) * DM + h * DK;
  const unsigned long long* mrow = mbits + ((size_t)(b * S_) + qbase + w * 16 + l4 * 4) * 32;

  // ======================= pass 1: l only (m == 0) =======================
  float lrun[4] = {0.f, 0.f, 0.f, 0.f};
#pragma unroll
  for (int i = 0; i < 2; ++i) {
    int row = i * 32 + srow;
    s16x8 v = *(const s16x8*)(Kbase + (size_t)row * DM + scol * 8);
    *(s16x8*)((char*)Ks[0] + row * 128 + ((scol * 16) ^ ((row & 7) << 4))) = v;
  }
  __syncthreads();
  for (int kt = 0; kt < 32; ++kt) {
    const int cur = kt & 1;
    const int nxt = (kt < 31) ? kt + 1 : kt;
    s16x8 rk0 = *(const s16x8*)(Kbase + (size_t)(nxt * 64 + srow) * DM + scol * 8);
    s16x8 rk1 = *(const s16x8*)(Kbase + (size_t)(nxt * 64 + 32 + srow) * DM + scol * 8);
    unsigned long long mws[4];
#pragma unroll
    for (int j = 0; j < 4; ++j) mws[j] = mrow[j * 32 + kt];
    f32x4 sacc[4] = {};
    __builtin_amdgcn_s_setprio(1);
#pragma unroll
    for (int nf = 0; nf < 4; ++nf) {
      int row = nf * 16 + lc;
#pragma unroll
      for (int kf = 0; kf < 2; ++kf) {
        s16x8 bk = *(const s16x8*)((char*)Ks[cur] + row * 128 +
                                   ((kf * 64 + l4 * 16) ^ ((row & 7) << 4)));
        sacc[nf] = MFMA_B16(kf ? aq1 : aq0, bk, sacc[nf]);
      }
    }
    __builtin_amdgcn_s_setprio(0);
#pragma unroll
    for (int j = 0; j < 4; ++j)
#pragma unroll
      for (int nf = 0; nf < 4; ++nf) {
        float e = __expf(sacc[nf][j] * 0.125f);
        lrun[j] += ((mws[j] >> (nf * 16 + lc)) & 1ull) ? 0.f : e;
      }
    *(s16x8*)((char*)Ks[cur ^ 1] + srow * 128 + ((scol * 16) ^ ((srow & 7) << 4))) = rk0;
    {
      int row = 32 + srow;
      *(s16x8*)((char*)Ks[cur ^ 1] + row * 128 + ((scol * 16) ^ ((row & 7) << 4))) = rk1;
    }
    __syncthreads();
  }
#pragma unroll
  for (int off = 1; off < 16; off <<= 1)
#pragma unroll
    for (int j = 0; j < 4; ++j) lrun[j] += __shfl_xor(lrun[j], off);
  float Li[4];
#pragma unroll
  for (int j = 0; j < 4; ++j) Li[j] = 1.f / lrun[j];

  // ======================= pass 2: write attn + PV =======================
#pragma unroll
  for (int i = 0; i < 2; ++i) {
    int row = i * 32 + srow;
    s16x8 v = *(const s16x8*)(Kbase + (size_t)row * DM + scol * 8);
    *(s16x8*)((char*)Ks[0] + row * 128 + ((scol * 16) ^ ((row & 7) << 4))) = v;
    s16x8 vv = *(const s16x8*)(Vbase + (size_t)row * DM + scol * 8);
#pragma unroll
    for (int jj = 0; jj < 8; ++jj) {
      int d = scol * 8 + jj;
      *(int16_t*)((char*)Vt + ((d * 128 + row * 2) ^ (scol << 4))) = vv[jj];
    }
  }
  __syncthreads();
  f32x4 cacc[4] = {};
  float* arow = attn_out + (((size_t)(b * H_ + h)) * S_ + qbase + w * 16) * S_;
  for (int kt = 0; kt < 32; ++kt) {
    const int cur = kt & 1;
    const int nxt = (kt < 31) ? kt + 1 : kt;
    s16x8 rk0 = *(const s16x8*)(Kbase + (size_t)(nxt * 64 + srow) * DM + scol * 8);
    s16x8 rk1 = *(const s16x8*)(Kbase + (size_t)(nxt * 64 + 32 + srow) * DM + scol * 8);
    s16x8 rv0 = *(const s16x8*)(Vbase + (size_t)(nxt * 64 + srow) * DM + scol * 8);
    s16x8 rv1 = *(const s16x8*)(Vbase + (size_t)(nxt * 64 + 32 + srow) * DM + scol * 8);
    unsigned long long mws[4];
#pragma unroll
    for (int j = 0; j < 4; ++j) mws[j] = mrow[j * 32 + kt];
    f32x4 sacc[4] = {};
    __builtin_amdgcn_s_setprio(1);
#pragma unroll
    for (int nf = 0; nf < 4; ++nf) {
      int row = nf * 16 + lc;
#pragma unroll
      for (int kf = 0; kf < 2; ++kf) {
        s16x8 bk = *(const s16x8*)((char*)Ks[cur] + row * 128 +
                                   ((kf * 64 + l4 * 16) ^ ((row & 7) << 4)));
        sacc[nf] = MFMA_B16(kf ? aq1 : aq0, bk, sacc[nf]);
      }
    }
    __builtin_amdgcn_s_setprio(0);
#pragma unroll
    for (int j = 0; j < 4; ++j)
#pragma unroll
      for (int nf = 0; nf < 4; ++nf) {
        float e = __expf(sacc[nf][j] * 0.125f);
        float p2 = ((mws[j] >> (nf * 16 + lc)) & 1ull) ? 0.f : e * Li[j];
        *(uint16_t*)((char*)Ps[w] + (l4 * 4 + j) * 144 + (nf * 16 + lc) * 2) = (uint16_t)bfr(p2);
      }
    s16x8 ap0 = *(const s16x8*)((char*)Ps[w] + lc * 144 + l4 * 16);
    s16x8 ap1 = *(const s16x8*)((char*)Ps[w] + lc * 144 + 64 + l4 * 16);
#pragma unroll
    for (int j = 0; j < 4; ++j) {
      const int r = j * 4 + (lane >> 4);
      s16x4 pv = *(const s16x4*)((char*)Ps[w] + r * 144 + (lane & 15) * 8);
      f32x4 o;
      o[0] = uf16(pv[0]); o[1] = uf16(pv[1]); o[2] = uf16(pv[2]); o[3] = uf16(pv[3]);
      __builtin_nontemporal_store(o,
          (f32x4*)(arow + (size_t)r * S_ + kt * 64 + (lane & 15) * 4));
    }
    __builtin_amdgcn_s_setprio(1);
#pragma unroll
    for (int nf = 0; nf < 4; ++nf) {
      int d = nf * 16 + lc;
#pragma unroll
      for (int kf = 0; kf < 2; ++kf) {
        s16x8 bv = *(const s16x8*)((char*)Vt +
                     ((d * 128 + kf * 64 + l4 * 16) ^ ((((d >> 3)) & 7) << 4)));
        cacc[nf] = MFMA_B16(kf ? ap1 : ap0, bv, cacc[nf]);
      }
    }
    __builtin_amdgcn_s_setprio(0);
    __syncthreads();
    *(s16x8*)((char*)Ks[cur ^ 1] + srow * 128 + ((scol * 16) ^ ((srow & 7) << 4))) = rk0;
    {
      int row = 32 + srow;
      *(s16x8*)((char*)Ks[cur ^ 1] + row * 128 + ((scol * 16) ^ ((row & 7) << 4))) = rk1;
    }
#pragma unroll
    for (int jj = 0; jj < 8; ++jj) {
      int d = scol * 8 + jj;
      *(int16_t*)((char*)Vt + ((d * 128 + srow * 2) ^ (scol << 4))) = rv0[jj];
      *(int16_t*)((char*)Vt + ((d * 128 + (32 + srow) * 2) ^ (scol << 4))) = rv1[jj];
    }
    __syncthreads();
  }
#pragma unroll
  for (int nf = 0; nf < 4; ++nf) {
    int d = nf * 16 + lc;
#pragma unroll
    for (int j = 0; j < 4; ++j) {
      int q = qbase + w * 16 + l4 * 4 + j;
      ctx[((size_t)(b * S_ + q)) * DM + h * DK + d] = (uint16_t)bfr(cacc[nf][j]);
    }
  }
}

// ---------------------------------------------------------------------------
// Residual + LayerNorm: out = LN(Y + Xq), one wave per 512-wide row
// ---------------------------------------------------------------------------
__global__ __launch_bounds__(256) void ln_k(const float* __restrict__ Y,
                                            const float* __restrict__ X,
                                            float* __restrict__ out) {
  const int lane = threadIdx.x & 63, w = threadIdx.x >> 6;
  const size_t row = (size_t)blockIdx.x * 4 + w;
  const float4* y = (const float4*)(Y + row * 512);
  const float4* x = (const float4*)(X + row * 512);
  float4 a0 = y[lane * 2], a1 = y[lane * 2 + 1];
  float4 b0 = x[lane * 2], b1 = x[lane * 2 + 1];
  float v[8] = {a0.x + b0.x, a0.y + b0.y, a0.z + b0.z, a0.w + b0.w,
                a1.x + b1.x, a1.y + b1.y, a1.z + b1.z, a1.w + b1.w};
  float s = 0.f, ss = 0.f;
#pragma unroll
  for (int j = 0; j < 8; ++j) { s += v[j]; ss += v[j] * v[j]; }
#pragma unroll
  for (int off = 1; off < 64; off <<= 1) {
    s += __shfl_xor(s, off);
    ss += __shfl_xor(ss, off);
  }
  float mean = s * (1.f / 512.f);
  float var = ss * (1.f / 512.f) - mean * mean;
  float rstd = rsqrtf(var + 1e-5f);
  float4 o0 = make_float4((v[0] - mean) * rstd, (v[1] - mean) * rstd,
                          (v[2] - mean) * rstd, (v[3] - mean) * rstd);
  float4 o1 = make_float4((v[4] - mean) * rstd, (v[5] - mean) * rstd,
                          (v[6] - mean) * rstd, (v[7] - mean) * rstd);
  float4* o = (float4*)(out + row * 512);
  o[lane * 2] = o0;
  o[lane * 2 + 1] = o1;
}

// ---------------------------------------------------------------------------
extern "C" void kernel_launch(void* const* d_in, const int* in_sizes, int n_in,
                              void* d_out, int out_size, void* d_ws, size_t ws_size,
                              hipStream_t stream) {
  const float* Xq = (const float*)d_in[0];
  const float* Xk = (const float*)d_in[1];
  const float* Xv = (const float*)d_in[2];
  const int*   mask = (const int*)d_in[3];
  const float* Wq = (const float*)d_in[4];
  const float* Wk = (const float*)d_in[5];
  const float* Wv = (const float*)d_in[6];
  const float* Wo = (const float*)d_in[7];

  float* out  = (float*)d_out;
  float* attn = out + (size_t)B_ * S_ * DM;

  char* ws = (char*)d_ws;
  uint16_t* Qb = (uint16_t*)(ws);                        //  0 .. 8M   bf16 [8192][512]
  uint16_t* Kb = (uint16_t*)(ws + (8u  << 20));          //  8 .. 16M
  uint16_t* Vb = (uint16_t*)(ws + (16u << 20));          // 16 .. 24M
  uint16_t* Cx = (uint16_t*)(ws + (24u << 20));          // 24 .. 32M  context bf16
  float*    Y  = (float*)   (ws + (32u << 20));          // 32 .. 48M  fp32 [8192][512]
  uint16_t* Wt = (uint16_t*)(ws + (48u << 20));          // 48 .. 50M  4x[512][512] bf16
  unsigned long long* mb = (unsigned long long*)(ws + (50u << 20));  // 50 .. 52M

  prep_k<<<2304, 256, 0, stream>>>(Wq, Wk, Wv, Wo, Wt, mask, mb);

  gemm3_k<true><<<768, 256, 0, stream>>>(Xq, Xk, Xv, Wt, nullptr, Qb, nullptr);

  attn_k<<<1024, 256, 0, stream>>>(Qb, Kb, Vb, mb, attn, Cx);

  gemm3_k<false><<<256, 256, 0, stream>>>(nullptr, nullptr, nullptr, Wt, Cx, nullptr, Y);
  ln_k<<<2048, 256, 0, stream>>>(Y, Xq, out);
}